// Round 3
// baseline (1141.990 us; speedup 1.0000x reference)
//
#include <hip/hip_runtime.h>
#include <hip/hip_bf16.h>
#include <math.h>

#define NTOK 2048
#define DIM  1024
#define SCALE 0.125f
#define MASK_VAL -65504.0f

typedef __attribute__((ext_vector_type(8))) short bf16x8;
typedef __attribute__((ext_vector_type(4))) float floatx4;

#define MFMA16(a,b,c) __builtin_amdgcn_mfma_f32_16x16x32_bf16((a),(b),(c),0,0,0)
#define GLL16(g,l) __builtin_amdgcn_global_load_lds( \
    (const __attribute__((address_space(1))) void*)(g), \
    (__attribute__((address_space(3))) void*)(l), 16, 0, 0)

__device__ __forceinline__ short f2bf(float f) {
  union { __hip_bfloat16 h; short s; } u;
  u.h = __float2bfloat16(f);
  return u.s;
}
__device__ __forceinline__ float bf2f(short s) {
  union { short s; __hip_bfloat16 h; } u;
  u.s = s;
  return __bfloat162float(u.h);
}

// ---------------------------------------------------------------- fp32 -> bf16
__global__ __launch_bounds__(256) void cvt_bf16(const float* __restrict__ in,
                                                short* __restrict__ out) {
  size_t i = ((size_t)blockIdx.x * 256 + threadIdx.x) * 4;
  float4 v = *(const float4*)(in + i);
  short4 o;
  o.x = f2bf(v.x); o.y = f2bf(v.y); o.z = f2bf(v.z); o.w = f2bf(v.w);
  *(short4*)(out + i) = o;
}

// ---------------------------------------------------------------- LayerNorm
__global__ __launch_bounds__(256) void ln_k(const float* __restrict__ x,
                                            const float* __restrict__ sc,
                                            const float* __restrict__ bi,
                                            short* __restrict__ out) {
  int row = blockIdx.x, t = threadIdx.x;
  float4 v = ((const float4*)(x + (size_t)row * DIM))[t];
  float s  = v.x + v.y + v.z + v.w;
  float s2 = v.x*v.x + v.y*v.y + v.z*v.z + v.w*v.w;
#pragma unroll
  for (int off = 32; off; off >>= 1) {
    s  += __shfl_xor(s, off);
    s2 += __shfl_xor(s2, off);
  }
  __shared__ float ps[4], ps2[4];
  if ((t & 63) == 0) { ps[t >> 6] = s; ps2[t >> 6] = s2; }
  __syncthreads();
  s  = ps[0] + ps[1] + ps[2] + ps[3];
  s2 = ps2[0] + ps2[1] + ps2[2] + ps2[3];
  float mu  = s * (1.0f / DIM);
  float inv = rsqrtf(s2 * (1.0f / DIM) - mu * mu + 1e-5f);
  float4 g = ((const float4*)sc)[t], b = ((const float4*)bi)[t];
  short4 o;
  o.x = f2bf((v.x - mu) * inv * g.x + b.x);
  o.y = f2bf((v.y - mu) * inv * g.y + b.y);
  o.z = f2bf((v.z - mu) * inv * g.z + b.z);
  o.w = f2bf((v.w - mu) * inv * g.w + b.w);
  ((short4*)(out + (size_t)row * DIM))[t] = o;
}

// ---------------------------------------------------------------- GEMM C = A @ B^T
// A: [M][K] bf16 row-major, B: [N][K] bf16 row-major (i.e. weight W[n][k]).
// 128x128 tile, BK=32, 256 threads = 4 waves, each wave 64x64 (4x4 of 16x16 MFMA).
enum { E_QKV = 0, E_RESID = 1, E_FC1 = 2 };

template <int EPI, int K>
__global__ __launch_bounds__(256) void gemm_bt(
    const short* __restrict__ A, const short* __restrict__ B,
    const float* __restrict__ bias0, const float* __restrict__ bias1,
    const float* __restrict__ resid, float* __restrict__ outf,
    short* __restrict__ o0, short* __restrict__ o1, short* __restrict__ o2) {
  __shared__ short As[128 * 32];
  __shared__ short Bs[128 * 32];
  const int t = threadIdx.x;
  const int bm = blockIdx.x, bn = blockIdx.y;
  const int l = t & 63, w = t >> 6;
  const int wr = w >> 1, wc = w & 1;
  const int lr = l & 15, lh = l >> 4;

  const short* ga = A + (size_t)(bm * 128 + (t >> 2)) * K + (t & 3) * 8;
  const short* gb = B + (size_t)(bn * 128 + (t >> 2)) * K + (t & 3) * 8;
  short* la = As + t * 8;
  short* lb = Bs + t * 8;

  floatx4 acc[4][4] = {};
  for (int kb = 0; kb < K / 32; ++kb) {
    GLL16(ga, la);
    GLL16(ga + (size_t)64 * K, la + 2048);
    GLL16(gb, lb);
    GLL16(gb + (size_t)64 * K, lb + 2048);
    ga += 32; gb += 32;
    __syncthreads();
    bf16x8 af[4], bfr[4];
#pragma unroll
    for (int m = 0; m < 4; m++)
      af[m] = *(const bf16x8*)(As + (wr * 64 + m * 16 + lr) * 32 + lh * 8);
#pragma unroll
    for (int n = 0; n < 4; n++)
      bfr[n] = *(const bf16x8*)(Bs + (wc * 64 + n * 16 + lr) * 32 + lh * 8);
#pragma unroll
    for (int m = 0; m < 4; m++)
#pragma unroll
      for (int n = 0; n < 4; n++)
        acc[m][n] = MFMA16(af[m], bfr[n], acc[m][n]);
    __syncthreads();
  }

#pragma unroll
  for (int m = 0; m < 4; m++) {
#pragma unroll
    for (int n = 0; n < 4; n++) {
#pragma unroll
      for (int j = 0; j < 4; j++) {
        int gr = bm * 128 + wr * 64 + m * 16 + lh * 4 + j;
        int gc = bn * 128 + wc * 64 + n * 16 + lr;
        float val = acc[m][n][j];
        if constexpr (EPI == E_QKV) {
          int which = gc >> 10, d = gc & 1023;
          int bb = gr >> 11, n_ = gr & 2047;
          size_t idx = (((size_t)bb * 16 + (d >> 6)) * NTOK + n_) * 64 + (d & 63);
          if (which == 0)      o0[idx] = f2bf((val + bias0[d]) * SCALE);
          else if (which == 1) o1[idx] = f2bf(val);
          else                 o2[idx] = f2bf(val + bias1[d]);
        } else if constexpr (EPI == E_RESID) {
          size_t idx = (size_t)gr * 1024 + gc;
          outf[idx] = val + bias0[gc] + resid[idx];
        } else {  // E_FC1: bias + exact GELU -> bf16
          float u = val + bias0[gc];
          float gelu = 0.5f * u * (1.0f + erff(u * 0.70710678f));
          o0[(size_t)gr * 4096 + gc] = f2bf(gelu);
        }
      }
    }
  }
}

// ---------------------------------------------------------------- V transpose
// v: [bh][n][64] -> vt: [bh][64][n]
__global__ __launch_bounds__(256) void transpose_v(const short* __restrict__ v,
                                                   short* __restrict__ vt) {
  __shared__ short tile[64][72];
  int bh = blockIdx.x, nb = blockIdx.y, t = threadIdx.x;
  int r = t >> 2, c0 = (t & 3) * 16;
  const short* src = v + ((size_t)bh * NTOK + nb * 64 + r) * 64 + c0;
  *(bf16x8*)&tile[r][c0]     = *(const bf16x8*)src;
  *(bf16x8*)&tile[r][c0 + 8] = *(const bf16x8*)(src + 8);
  __syncthreads();
  int d = t >> 2, n0 = (t & 3) * 16;
  bf16x8 a, b;
#pragma unroll
  for (int i = 0; i < 8; i++) { a[i] = tile[n0 + i][d]; b[i] = tile[n0 + 8 + i][d]; }
  short* dst = vt + ((size_t)bh * 64 + d) * NTOK + nb * 64 + n0;
  *(bf16x8*)dst       = a;
  *(bf16x8*)(dst + 8) = b;
}

// ---------------------------------------------------------------- fused attention
// One block = one (b,h) and 16 q-rows. S row-block (16x2048 bf16, XOR-swizzled)
// in exactly 64KB LDS. Writes normalized attn (fp32) to d_out and PV result (bf16).
__global__ __launch_bounds__(256) void attn_k(
    const short* __restrict__ q, const short* __restrict__ k,
    const short* __restrict__ vt, const int* __restrict__ mask,
    const float* __restrict__ bias, float* __restrict__ attn_out,
    short* __restrict__ out) {
  __shared__ short S[16 * NTOK];
  int blk = blockIdx.x;
  int qt = blk & 127, bh = blk >> 7;
  int b = bh >> 4, h = bh & 15;
  int q0 = qt * 16;
  int t = threadIdx.x, l = t & 63, w = t >> 6;
  int lr = l & 15, lh = l >> 4;

  // ---- QK^T (each wave owns 512 key columns)
  const short* qb = q + ((size_t)bh * NTOK + q0 + lr) * 64 + lh * 8;
  bf16x8 aq0 = *(const bf16x8*)qb;
  bf16x8 aq1 = *(const bf16x8*)(qb + 32);
  for (int ct = w * 32; ct < w * 32 + 32; ++ct) {
    const short* kb = k + ((size_t)bh * NTOK + ct * 16 + lr) * 64 + lh * 8;
    bf16x8 bk0 = *(const bf16x8*)kb;
    bf16x8 bk1 = *(const bf16x8*)(kb + 32);
    floatx4 s4 = {};
    s4 = MFMA16(aq0, bk0, s4);
    s4 = MFMA16(aq1, bk1, s4);
    int m = ct * 16 + lr;
    int msk = mask[b * NTOK + m];
#pragma unroll
    for (int j = 0; j < 4; j++) {
      int r = lh * 4 + j;
      float val = msk ? MASK_VAL : s4[j];
      val += bias[(size_t)(q0 + r) * NTOK + m];
      *(short*)((char*)S + r * 4096 + ((m * 2) ^ ((r & 7) << 4))) = f2bf(val);
    }
  }
  __syncthreads();

  // ---- softmax: 16 threads per row
  int r2 = t >> 4, g = t & 15;
  char* Srow = (char*)S + r2 * 4096;
  int swz = (r2 & 7) << 4;
  float mx = -3.0e38f;
#pragma unroll
  for (int i = 0; i < 16; i++) {
    int mb = (g + (i << 4)) << 4;  // byte offset of 8-element chunk
    bf16x8 p = *(const bf16x8*)(Srow + (mb ^ swz));
#pragma unroll
    for (int j = 0; j < 8; j++) mx = fmaxf(mx, bf2f(p[j]));
  }
#pragma unroll
  for (int off = 8; off; off >>= 1) mx = fmaxf(mx, __shfl_xor(mx, off));
  float sum = 0.f;
#pragma unroll
  for (int i = 0; i < 16; i++) {
    int mb = (g + (i << 4)) << 4;
    bf16x8* pp = (bf16x8*)(Srow + (mb ^ swz));
    bf16x8 p = *pp, e8;
#pragma unroll
    for (int j = 0; j < 8; j++) {
      float e = __expf(bf2f(p[j]) - mx);
      sum += e;
      e8[j] = f2bf(e);
    }
    *pp = e8;
  }
#pragma unroll
  for (int off = 8; off; off >>= 1) sum += __shfl_xor(sum, off);
  float inv = 1.0f / sum;

  // ---- normalize: write attn fp32 to global, normalized bf16 back to LDS
  float* arow = attn_out + ((size_t)bh * NTOK + q0 + r2) * NTOK;
#pragma unroll
  for (int i = 0; i < 16; i++) {
    int m0 = (g + (i << 4)) << 3;
    bf16x8* pp = (bf16x8*)(Srow + ((m0 * 2) ^ swz));
    bf16x8 p = *pp, pn;
    float4 f0, f1;
    float pv0 = bf2f(p[0]) * inv, pv1 = bf2f(p[1]) * inv,
          pv2 = bf2f(p[2]) * inv, pv3 = bf2f(p[3]) * inv;
    float pv4 = bf2f(p[4]) * inv, pv5 = bf2f(p[5]) * inv,
          pv6 = bf2f(p[6]) * inv, pv7 = bf2f(p[7]) * inv;
    pn[0] = f2bf(pv0); pn[1] = f2bf(pv1); pn[2] = f2bf(pv2); pn[3] = f2bf(pv3);
    pn[4] = f2bf(pv4); pn[5] = f2bf(pv5); pn[6] = f2bf(pv6); pn[7] = f2bf(pv7);
    f0.x = pv0; f0.y = pv1; f0.z = pv2; f0.w = pv3;
    f1.x = pv4; f1.y = pv5; f1.z = pv6; f1.w = pv7;
    *(float4*)(arow + m0)     = f0;
    *(float4*)(arow + m0 + 4) = f1;
    *pp = pn;
  }
  __syncthreads();

  // ---- PV: each wave computes 16 q-rows x 16 head-dims
  floatx4 o4 = {};
  const short* vtb = vt + ((size_t)bh * 64 + w * 16 + lr) * NTOK;
  char* Sb = (char*)S + lr * 4096;
  int swzr = (lr & 7) << 4;
  for (int kt = 0; kt < 64; ++kt) {
    bf16x8 a  = *(const bf16x8*)(Sb + ((kt * 64 + lh * 16) ^ swzr));
    bf16x8 bv = *(const bf16x8*)(vtb + kt * 32 + lh * 8);
    o4 = MFMA16(a, bv, o4);
  }
#pragma unroll
  for (int j = 0; j < 4; j++) {
    int r = lh * 4 + j;
    out[((size_t)b * NTOK + q0 + r) * DIM + h * 64 + w * 16 + lr] = f2bf(o4[j]);
  }
}

// ---------------------------------------------------------------- launch
extern "C" void kernel_launch(void* const* d_in, const int* in_sizes, int n_in,
                              void* d_out, int out_size, void* d_ws, size_t ws_size,
                              hipStream_t stream) {
  const float* x      = (const float*)d_in[0];
  const int*   mask   = (const int*)d_in[1];
  const float* abias  = (const float*)d_in[2];
  const float* qkv_w  = (const float*)d_in[3];
  const float* q_bias = (const float*)d_in[4];
  const float* v_bias = (const float*)d_in[5];
  const float* proj_w = (const float*)d_in[6];
  const float* proj_b = (const float*)d_in[7];
  const float* ln1_s  = (const float*)d_in[8];
  const float* ln1_b  = (const float*)d_in[9];
  const float* ln2_s  = (const float*)d_in[10];
  const float* ln2_b  = (const float*)d_in[11];
  const float* fc1_w  = (const float*)d_in[12];
  const float* fc1_b  = (const float*)d_in[13];
  const float* fc2_w  = (const float*)d_in[14];
  const float* fc2_b  = (const float*)d_in[15];

  char* ws = (char*)d_ws;
  short* wq   = (short*)(ws + 0);          //  6 MB  qkv_w bf16
  short* wp   = (short*)(ws + 6291456);    //  2 MB  proj_w bf16
  short* w1   = (short*)(ws + 8388608);    //  8 MB  fc1_w bf16
  short* w2   = (short*)(ws + 16777216);   //  8 MB  fc2_w bf16
  float* x1   = (float*)(ws + 25165824);   // 16 MB  residual-1 fp32
  short* hbuf = (short*)(ws + 41943040);   //  8 MB  h / attn-out / h2 (aliased)
  short* qb   = (short*)(ws + 50331648);   //  8 MB  q bf16
  short* kb   = (short*)(ws + 58720256);   //  8 MB  k bf16
  short* vb   = (short*)(ws + 67108864);   //  8 MB  v bf16
  short* vtb  = (short*)(ws + 75497472);   //  8 MB  v^T bf16
  short* h3   = (short*)(ws + 50331648);   // 32 MB  fc1 out (aliases q..vt)

  float* out_x    = (float*)d_out;
  float* out_attn = (float*)d_out + 4194304;

  // weights -> bf16
  cvt_bf16<<<3072, 256, 0, stream>>>(qkv_w, wq);
  cvt_bf16<<<1024, 256, 0, stream>>>(proj_w, wp);
  cvt_bf16<<<4096, 256, 0, stream>>>(fc1_w, w1);
  cvt_bf16<<<4096, 256, 0, stream>>>(fc2_w, w2);

  // LN1
  ln_k<<<4096, 256, 0, stream>>>(x, ln1_s, ln1_b, hbuf);

  // QKV projection (M=4096, N=3072, K=1024)
  gemm_bt<E_QKV, 1024><<<dim3(32, 24), 256, 0, stream>>>(
      hbuf, wq, q_bias, v_bias, nullptr, nullptr, qb, kb, vb);

  // V transpose
  transpose_v<<<dim3(32, 32), 256, 0, stream>>>(vb, vtb);

  // fused attention (+ writes attn output)
  attn_k<<<4096, 256, 0, stream>>>(qb, kb, vtb, mask, abias, out_attn, hbuf);

  // out projection + residual (M=4096, N=1024, K=1024)
  gemm_bt<E_RESID, 1024><<<dim3(32, 8), 256, 0, stream>>>(
      hbuf, wp, proj_b, nullptr, x, x1, nullptr, nullptr, nullptr);

  // LN2
  ln_k<<<4096, 256, 0, stream>>>(x1, ln2_s, ln2_b, hbuf);

  // FC1 + GELU (M=4096, N=4096, K=1024)
  gemm_bt<E_FC1, 1024><<<dim3(32, 32), 256, 0, stream>>>(
      hbuf, w1, fc1_b, nullptr, nullptr, nullptr, h3, nullptr, nullptr);

  // FC2 + residual (M=4096, N=1024, K=4096)
  gemm_bt<E_RESID, 4096><<<dim3(32, 8), 256, 0, stream>>>(
      h3, w2, fc2_b, nullptr, x1, out_x, nullptr, nullptr, nullptr);
}